// Round 5
// baseline (255.469 us; speedup 1.0000x reference)
//
#include <hip/hip_runtime.h>

typedef unsigned short ushort_t;
typedef __attribute__((ext_vector_type(8))) __bf16 bf16x8;
typedef __attribute__((ext_vector_type(4))) float f32x4;

#define NB 4
#define NL 4096
#define ND 1024
#define NH 16
#define NDH 64
#define NM (NB*NL)   // 16384

__device__ __forceinline__ ushort_t f2bf(float f) {
  unsigned u = __builtin_bit_cast(unsigned, f);
  u += 0x7fffu + ((u >> 16) & 1u);
  return (ushort_t)(u >> 16);
}

// ---------------- fp32 -> bf16 conversion ----------------
__global__ __launch_bounds__(256) void k_cvt(const float* __restrict__ in,
                                             ushort_t* __restrict__ out, int n4) {
  int i = blockIdx.x * 256 + threadIdx.x;
  int stride = gridDim.x * 256;
  for (; i < n4; i += stride) {
    float4 v = ((const float4*)in)[i];
    ushort4 o;
    o.x = f2bf(v.x); o.y = f2bf(v.y); o.z = f2bf(v.z); o.w = f2bf(v.w);
    ((ushort4*)out)[i] = o;
  }
}

// ---------------- GEMM: C[M][N] = A[M][K] * Bt[N][K]^T ----------------
// MODE 0: C bf16 row-major.  MODE 2: C fp32 row-major.
template<int MODE>
__global__ __launch_bounds__(256) void k_gemm(
    const ushort_t* __restrict__ A, const ushort_t* __restrict__ Bt,
    void* __restrict__ Cout, int M, int N, int K)
{
  __shared__ __align__(16) ushort_t As[128*32];
  __shared__ __align__(16) ushort_t Bs[128*32];
  const int tid = threadIdx.x;
  const int lane = tid & 63, wave = tid >> 6;
  const int rowBase = blockIdx.y * 128, colBase = blockIdx.x * 128;

  const int e0 = tid * 8;
  const int ar0 = e0 >> 5, ac0 = e0 & 31;
  const int e1 = 2048 + tid * 8;
  const int ar1 = e1 >> 5, ac1 = e1 & 31;

  const ushort_t* Ag0 = A + (size_t)(rowBase + ar0) * K + ac0;
  const ushort_t* Ag1 = A + (size_t)(rowBase + ar1) * K + ac1;
  const ushort_t* Bg0 = Bt + (size_t)(colBase + ar0) * K + ac0;
  const ushort_t* Bg1 = Bt + (size_t)(colBase + ar1) * K + ac1;

  const int wr = wave >> 1, wc = wave & 1;
  const int l15 = lane & 15, lhi = lane >> 4;
  const int arow = wr * 64 + l15;
  const int brow = wc * 64 + l15;
  const int kOff = lhi * 8;

  f32x4 acc[4][4] = {};

  for (int kt = 0; kt < K; kt += 32) {
    bf16x8 a0 = *(const bf16x8*)(Ag0 + kt);
    bf16x8 a1 = *(const bf16x8*)(Ag1 + kt);
    bf16x8 b0 = *(const bf16x8*)(Bg0 + kt);
    bf16x8 b1 = *(const bf16x8*)(Bg1 + kt);
    *(bf16x8*)&As[e0] = a0;
    *(bf16x8*)&As[e1] = a1;
    *(bf16x8*)&Bs[e0] = b0;
    *(bf16x8*)&Bs[e1] = b1;
    __syncthreads();
    bf16x8 af[4], bfr[4];
#pragma unroll
    for (int i = 0; i < 4; ++i) af[i]  = *(const bf16x8*)&As[(arow + i*16)*32 + kOff];
#pragma unroll
    for (int j = 0; j < 4; ++j) bfr[j] = *(const bf16x8*)&Bs[(brow + j*16)*32 + kOff];
#pragma unroll
    for (int i = 0; i < 4; ++i)
#pragma unroll
      for (int j = 0; j < 4; ++j)
        acc[i][j] = __builtin_amdgcn_mfma_f32_16x16x32_bf16(af[i], bfr[j], acc[i][j], 0, 0, 0);
    __syncthreads();
  }

#pragma unroll
  for (int i = 0; i < 4; ++i)
#pragma unroll
    for (int j = 0; j < 4; ++j)
#pragma unroll
      for (int r = 0; r < 4; ++r) {
        int gr = rowBase + wr*64 + i*16 + lhi*4 + r;
        int gc = colBase + wc*64 + j*16 + l15;
        float v = acc[i][j][r];
        if (MODE == 2) ((float*)Cout)[(size_t)gr * N + gc] = v;
        else           ((ushort_t*)Cout)[(size_t)gr * N + gc] = f2bf(v);
      }
}

// ---------------- per-token attention over HEADS ----------------
// qkv: [NM][3072] bf16  (cols 0..1023: q at h*64+dh; 1024..3071: kv at h*128 + s*64 + dh)
// aout: [NM][1024] bf16 (col = h*64 + d)
// One wave per token. Per token: S[h][j] = q_h . k_j / 8 (16x16), softmax over j,
// O[h][d] = sum_j P[h][j] v_j[d].
__global__ __launch_bounds__(256) void k_attn(
    const ushort_t* __restrict__ qkv, ushort_t* __restrict__ aout)
{
  __shared__ __align__(16) ushort_t qs[4][16*72];    // q padded rows (72)
  __shared__ __align__(16) ushort_t kvs[4][16*136];  // k|v padded rows (136): k at 0..63, v at 64..127
  __shared__ __align__(16) ushort_t ps[4][16*40];    // P padded rows (40), cols 16..31 zero
  __shared__ __align__(16) ushort_t os[4][1024];     // O staging
  const int tid = threadIdx.x, lane = tid & 63, wave = tid >> 6;
  const int t = blockIdx.x * 4 + wave;
  const int l15 = lane & 15, lhi = lane >> 4;
  const ushort_t* row = qkv + (size_t)t * 3072;

  // stage 3072 elems = 384 vec8 chunks; 6 per lane, coalesced
#pragma unroll
  for (int c = 0; c < 6; ++c) {
    int c8 = c * 64 + lane;
    bf16x8 v = *(const bf16x8*)(row + c8 * 8);
    if (c8 < 128) {                       // q region
      int h = c8 >> 3, off = (c8 & 7) * 8;
      *(bf16x8*)&qs[wave][h*72 + off] = v;
    } else {                              // kv region
      int e = c8 * 8 - 1024;
      int h = e >> 7, off = e & 127;
      *(bf16x8*)&kvs[wave][h*136 + off] = v;
    }
  }
  // zero the padded P columns 16..31 (A-operand k=16..31 reads these)
  if (lane < 16) {
    bf16x8 z = {};
    *(bf16x8*)&ps[wave][lane*40 + 16] = z;
    *(bf16x8*)&ps[wave][lane*40 + 24] = z;
  }
  __syncthreads();

  // S = q k^T: A rows = h (m=l15), B rows = j (n=l15), k-dim = d (lhi*8 + i + 32*ks)
  bf16x8 aq0 = *(const bf16x8*)&qs[wave][l15*72 + lhi*8];
  bf16x8 aq1 = *(const bf16x8*)&qs[wave][l15*72 + 32 + lhi*8];
  bf16x8 bk0 = *(const bf16x8*)&kvs[wave][l15*136 + lhi*8];
  bf16x8 bk1 = *(const bf16x8*)&kvs[wave][l15*136 + 32 + lhi*8];
  f32x4 s = {};
  s = __builtin_amdgcn_mfma_f32_16x16x32_bf16(aq0, bk0, s, 0, 0, 0);
  s = __builtin_amdgcn_mfma_f32_16x16x32_bf16(aq1, bk1, s, 0, 0, 0);

  // softmax over j (= lane l15 group) for each row h = lhi*4 + r; normalize P
#pragma unroll
  for (int r = 0; r < 4; ++r) {
    float sv = s[r] * 0.125f;
    float tm = sv;
#pragma unroll
    for (int off = 1; off < 16; off <<= 1) tm = fmaxf(tm, __shfl_xor(tm, off, 64));
    float p = __expf(sv - tm);
    float rs = p;
#pragma unroll
    for (int off = 1; off < 16; off <<= 1) rs += __shfl_xor(rs, off, 64);
    p /= rs;
    ps[wave][(lhi*4 + r)*40 + l15] = f2bf(p);
  }
  __syncthreads();

  // O = P V: A = P [16 rows h][K=32 padded j], B^T: lane n = d = dt*16+l15, k = j
  bf16x8 pa = *(const bf16x8*)&ps[wave][l15*40 + lhi*8];   // k = lhi*8 + i (0..31)
#pragma unroll
  for (int dt = 0; dt < 4; ++dt) {
    bf16x8 vb;
#pragma unroll
    for (int i = 0; i < 8; ++i) {
      int j = (lhi*8 + i) & 15;   // wrap for k>=16: P=0 there, value don't-care
      vb[i] = __builtin_bit_cast(__bf16, kvs[wave][j*136 + 64 + dt*16 + l15]);
    }
    f32x4 o = {};
    o = __builtin_amdgcn_mfma_f32_16x16x32_bf16(pa, vb, o, 0, 0, 0);
#pragma unroll
    for (int r = 0; r < 4; ++r)
      os[wave][(lhi*4 + r)*64 + dt*16 + l15] = f2bf(o[r]);
  }
  __syncthreads();

  // coalesced write: 1024 elems = 128 vec8, 2 per lane
  ushort_t* orow = aout + (size_t)t * 1024;
#pragma unroll
  for (int c = 0; c < 2; ++c) {
    int idx = (c*64 + lane) * 8;
    *(bf16x8*)(orow + idx) = *(const bf16x8*)&os[wave][idx];
  }
}

extern "C" void kernel_launch(void* const* d_in, const int* in_sizes, int n_in,
                              void* d_out, int out_size, void* d_ws, size_t ws_size,
                              hipStream_t stream) {
  const float* x    = (const float*)d_in[0];
  const float* Wq   = (const float*)d_in[1];
  const float* Wkv  = (const float*)d_in[2];
  const float* Wout = (const float*)d_in[3];
  float* out = (float*)d_out;

  ushort_t* ws    = (ushort_t*)d_ws;
  ushort_t* xb    = ws;                          // 16,777,216 elems (reused as aout)
  ushort_t* Wcat  = xb + 16777216;               // 3,145,728  (Wq ; Wkv)
  ushort_t* Woutb = Wcat + 3145728;              // 1,048,576
  ushort_t* qkv   = Woutb + 1048576;             // 50,331,648 ([M][3072])
  ushort_t* aout  = xb;                          // alias: xb dead after gemm1

  // fp32 -> bf16
  k_cvt<<<2048, 256, 0, stream>>>(x,    xb,   16777216/4);
  k_cvt<<<256,  256, 0, stream>>>(Wq,   Wcat, 1048576/4);
  k_cvt<<<512,  256, 0, stream>>>(Wkv,  Wcat + 1048576, 2097152/4);
  k_cvt<<<256,  256, 0, stream>>>(Wout, Woutb, 1048576/4);

  // QKV projection: [16384 x 1024] x [3072 x 1024]^T -> qkv row-major
  dim3 g1(24, 128);
  k_gemm<0><<<g1, 256, 0, stream>>>(xb, Wcat, qkv, NM, 3072, ND);

  // per-token attention over heads
  k_attn<<<NM/4, 256, 0, stream>>>(qkv, aout);

  // output projection: [16384 x 1024] x [1024 x 1024]^T -> fp32
  dim3 g3(8, 128);
  k_gemm<2><<<g3, 256, 0, stream>>>(aout, Woutb, out, NM, ND, ND);
}

// Round 6
// 251.259 us; speedup vs baseline: 1.0168x; 1.0168x over previous
//
#include <hip/hip_runtime.h>

typedef unsigned short ushort_t;
typedef __attribute__((ext_vector_type(8))) __bf16 bf16x8;
typedef __attribute__((ext_vector_type(4))) float f32x4;

#define NB 4
#define NL 4096
#define ND 1024
#define NH 16
#define NDH 64
#define NM (NB*NL)   // 16384

__device__ __forceinline__ ushort_t f2bf(float f) {
  unsigned u = __builtin_bit_cast(unsigned, f);
  u += 0x7fffu + ((u >> 16) & 1u);
  return (ushort_t)(u >> 16);
}

__device__ __forceinline__ void gl_lds16(const void* g, void* l) {
  __builtin_amdgcn_global_load_lds(
      (const __attribute__((address_space(1))) unsigned*)g,
      (__attribute__((address_space(3))) unsigned*)l, 16, 0, 0);
}

// ---------------- fused fp32 -> bf16 conversion (all 4 tensors) ----------------
__global__ __launch_bounds__(256) void k_cvt4(
    const float* __restrict__ x, const float* __restrict__ Wq,
    const float* __restrict__ Wkv, const float* __restrict__ Wout,
    ushort_t* __restrict__ xb, ushort_t* __restrict__ Wcat,
    ushort_t* __restrict__ Woutb)
{
  int i = blockIdx.x * 256 + threadIdx.x;
  const int stride = gridDim.x * 256;
  // segment boundaries in float4 units
  // x: [0, 4194304)  Wq: [.., +262144)  Wkv: [.., +524288)  Wout: [.., +262144)
  for (; i < 5242880; i += stride) {
    const float4* src; ushort4* dst; int off;
    if (i < 4194304)      { src = (const float4*)x;    dst = (ushort4*)xb;                 off = i; }
    else if (i < 4456448) { src = (const float4*)Wq;   dst = (ushort4*)Wcat;               off = i - 4194304; }
    else if (i < 4980736) { src = (const float4*)Wkv;  dst = (ushort4*)(Wcat + 1048576);   off = i - 4456448; }
    else                  { src = (const float4*)Wout; dst = (ushort4*)Woutb;              off = i - 4980736; }
    float4 v = src[off];
    ushort4 o;
    o.x = f2bf(v.x); o.y = f2bf(v.y); o.z = f2bf(v.z); o.w = f2bf(v.w);
    dst[off] = o;
  }
}

// ---------------- GEMM: C[M][N] = A[M][K] * Bt[N][K]^T ----------------
// MODE 0: C bf16 row-major.  MODE 2: C fp32 row-major.
// m97 structure: 128^2 tile, BK=32, global_load_lds width-16 staging.
template<int MODE>
__global__ __launch_bounds__(256) void k_gemm(
    const ushort_t* __restrict__ A, const ushort_t* __restrict__ Bt,
    void* __restrict__ Cout, int M, int N, int K)
{
  __shared__ __align__(16) ushort_t As[128*32];
  __shared__ __align__(16) ushort_t Bs[128*32];
  const int tid = threadIdx.x;
  const int lane = tid & 63, wave = tid >> 6;
  const int rowBase = blockIdx.y * 128, colBase = blockIdx.x * 128;

  // staging coords: tile is 128x32 = 4096 elems; 2 DMA rounds x 256 thr x 8 elems
  const int e0 = tid * 8;
  const int ar0 = e0 >> 5, ac0 = e0 & 31;
  const int e1 = 2048 + tid * 8;
  const int ar1 = e1 >> 5, ac1 = e1 & 31;

  const ushort_t* Ag0 = A + (size_t)(rowBase + ar0) * K + ac0;
  const ushort_t* Ag1 = A + (size_t)(rowBase + ar1) * K + ac1;
  const ushort_t* Bg0 = Bt + (size_t)(colBase + ar0) * K + ac0;
  const ushort_t* Bg1 = Bt + (size_t)(colBase + ar1) * K + ac1;

  const int wr = wave >> 1, wc = wave & 1;
  const int l15 = lane & 15, lhi = lane >> 4;
  const int arow = wr * 64 + l15;
  const int brow = wc * 64 + l15;
  const int kOff = lhi * 8;

  f32x4 acc[4][4] = {};

  for (int kt = 0; kt < K; kt += 32) {
    gl_lds16(Ag0 + kt, &As[wave * 512]);
    gl_lds16(Ag1 + kt, &As[2048 + wave * 512]);
    gl_lds16(Bg0 + kt, &Bs[wave * 512]);
    gl_lds16(Bg1 + kt, &Bs[2048 + wave * 512]);
    __syncthreads();
    bf16x8 af[4], bfr[4];
#pragma unroll
    for (int i = 0; i < 4; ++i) af[i]  = *(const bf16x8*)&As[(arow + i*16)*32 + kOff];
#pragma unroll
    for (int j = 0; j < 4; ++j) bfr[j] = *(const bf16x8*)&Bs[(brow + j*16)*32 + kOff];
#pragma unroll
    for (int i = 0; i < 4; ++i)
#pragma unroll
      for (int j = 0; j < 4; ++j)
        acc[i][j] = __builtin_amdgcn_mfma_f32_16x16x32_bf16(af[i], bfr[j], acc[i][j], 0, 0, 0);
    __syncthreads();
  }

#pragma unroll
  for (int i = 0; i < 4; ++i)
#pragma unroll
    for (int j = 0; j < 4; ++j)
#pragma unroll
      for (int r = 0; r < 4; ++r) {
        int gr = rowBase + wr*64 + i*16 + lhi*4 + r;
        int gc = colBase + wc*64 + j*16 + l15;
        float v = acc[i][j][r];
        if (MODE == 2) ((float*)Cout)[(size_t)gr * N + gc] = v;
        else           ((ushort_t*)Cout)[(size_t)gr * N + gc] = f2bf(v);
      }
}

// ---------------- per-token attention over HEADS ----------------
// qkv: [NM][3072] bf16  (cols 0..1023: q at h*64+dh; 1024..3071: kv at h*128 + s*64 + dh)
// aout: [NM][1024] bf16 (col = h*64 + d)
__global__ __launch_bounds__(256) void k_attn(
    const ushort_t* __restrict__ qkv, ushort_t* __restrict__ aout)
{
  __shared__ __align__(16) ushort_t qs[4][16*72];    // q padded rows (72)
  __shared__ __align__(16) ushort_t kvs[4][16*136];  // k|v padded rows (136): k at 0..63, v at 64..127
  __shared__ __align__(16) ushort_t ps[4][16*40];    // P padded rows (40), cols 16..31 zero
  __shared__ __align__(16) ushort_t os[4][1024];     // O staging
  const int tid = threadIdx.x, lane = tid & 63, wave = tid >> 6;
  const int t = blockIdx.x * 4 + wave;
  const int l15 = lane & 15, lhi = lane >> 4;
  const ushort_t* row = qkv + (size_t)t * 3072;

  // stage 3072 elems = 384 vec8 chunks; 6 per lane, coalesced
#pragma unroll
  for (int c = 0; c < 6; ++c) {
    int c8 = c * 64 + lane;
    bf16x8 v = *(const bf16x8*)(row + c8 * 8);
    if (c8 < 128) {                       // q region
      int h = c8 >> 3, off = (c8 & 7) * 8;
      *(bf16x8*)&qs[wave][h*72 + off] = v;
    } else {                              // kv region
      int e = c8 * 8 - 1024;
      int h = e >> 7, off = e & 127;
      *(bf16x8*)&kvs[wave][h*136 + off] = v;
    }
  }
  // zero the padded P columns 16..31 (A-operand k=16..31 reads these)
  if (lane < 16) {
    bf16x8 z = {};
    *(bf16x8*)&ps[wave][lane*40 + 16] = z;
    *(bf16x8*)&ps[wave][lane*40 + 24] = z;
  }
  __syncthreads();

  // S = q k^T: A rows = h (m=l15), B rows = j (n=l15), k-dim = d
  bf16x8 aq0 = *(const bf16x8*)&qs[wave][l15*72 + lhi*8];
  bf16x8 aq1 = *(const bf16x8*)&qs[wave][l15*72 + 32 + lhi*8];
  bf16x8 bk0 = *(const bf16x8*)&kvs[wave][l15*136 + lhi*8];
  bf16x8 bk1 = *(const bf16x8*)&kvs[wave][l15*136 + 32 + lhi*8];
  f32x4 s = {};
  s = __builtin_amdgcn_mfma_f32_16x16x32_bf16(aq0, bk0, s, 0, 0, 0);
  s = __builtin_amdgcn_mfma_f32_16x16x32_bf16(aq1, bk1, s, 0, 0, 0);

  // softmax over j for each row h = lhi*4 + r; normalize P
#pragma unroll
  for (int r = 0; r < 4; ++r) {
    float sv = s[r] * 0.125f;
    float tm = sv;
#pragma unroll
    for (int off = 1; off < 16; off <<= 1) tm = fmaxf(tm, __shfl_xor(tm, off, 64));
    float p = __expf(sv - tm);
    float rs = p;
#pragma unroll
    for (int off = 1; off < 16; off <<= 1) rs += __shfl_xor(rs, off, 64);
    p /= rs;
    ps[wave][(lhi*4 + r)*40 + l15] = f2bf(p);
  }
  __syncthreads();

  // O = P V
  bf16x8 pa = *(const bf16x8*)&ps[wave][l15*40 + lhi*8];
#pragma unroll
  for (int dt = 0; dt < 4; ++dt) {
    bf16x8 vb;
#pragma unroll
    for (int i = 0; i < 8; ++i) {
      int j = (lhi*8 + i) & 15;   // wrap for k>=16: P=0 there, value don't-care
      vb[i] = __builtin_bit_cast(__bf16, kvs[wave][j*136 + 64 + dt*16 + l15]);
    }
    f32x4 o = {};
    o = __builtin_amdgcn_mfma_f32_16x16x32_bf16(pa, vb, o, 0, 0, 0);
#pragma unroll
    for (int r = 0; r < 4; ++r)
      os[wave][(lhi*4 + r)*64 + dt*16 + l15] = f2bf(o[r]);
  }
  __syncthreads();

  // coalesced write: 1024 elems = 128 vec8, 2 per lane
  ushort_t* orow = aout + (size_t)t * 1024;
#pragma unroll
  for (int c = 0; c < 2; ++c) {
    int idx = (c*64 + lane) * 8;
    *(bf16x8*)(orow + idx) = *(const bf16x8*)&os[wave][idx];
  }
}

extern "C" void kernel_launch(void* const* d_in, const int* in_sizes, int n_in,
                              void* d_out, int out_size, void* d_ws, size_t ws_size,
                              hipStream_t stream) {
  const float* x    = (const float*)d_in[0];
  const float* Wq   = (const float*)d_in[1];
  const float* Wkv  = (const float*)d_in[2];
  const float* Wout = (const float*)d_in[3];
  float* out = (float*)d_out;

  ushort_t* ws    = (ushort_t*)d_ws;
  ushort_t* xb    = ws;                          // 16,777,216 elems (reused as aout)
  ushort_t* Wcat  = xb + 16777216;               // 3,145,728  (Wq ; Wkv)
  ushort_t* Woutb = Wcat + 3145728;              // 1,048,576
  ushort_t* qkv   = Woutb + 1048576;             // 50,331,648 ([M][3072])
  ushort_t* aout  = xb;                          // alias: xb dead after gemm1

  // fused fp32 -> bf16
  k_cvt4<<<2048, 256, 0, stream>>>(x, Wq, Wkv, Wout, xb, Wcat, Woutb);

  // QKV projection: [16384 x 1024] x [3072 x 1024]^T -> qkv row-major
  dim3 g1(24, 128);
  k_gemm<0><<<g1, 256, 0, stream>>>(xb, Wcat, qkv, NM, 3072, ND);

  // per-token attention over heads
  k_attn<<<NM/4, 256, 0, stream>>>(qkv, aout);

  // output projection: [16384 x 1024] x [1024 x 1024]^T -> fp32
  dim3 g3(8, 128);
  k_gemm<2><<<g3, 256, 0, stream>>>(aout, Woutb, out, NM, ND, ND);
}

// Round 7
// 222.451 us; speedup vs baseline: 1.1484x; 1.1295x over previous
//
#include <hip/hip_runtime.h>

typedef unsigned short ushort_t;
typedef __attribute__((ext_vector_type(8))) __bf16 bf16x8;
typedef __attribute__((ext_vector_type(4))) float f32x4;

#define NB 4
#define NL 4096
#define ND 1024
#define NH 16
#define NDH 64
#define NM (NB*NL)   // 16384

__device__ __forceinline__ ushort_t f2bf(float f) {
  unsigned u = __builtin_bit_cast(unsigned, f);
  u += 0x7fffu + ((u >> 16) & 1u);
  return (ushort_t)(u >> 16);
}

__device__ __forceinline__ void gl_lds16(const void* g, void* l) {
  __builtin_amdgcn_global_load_lds(
      (const __attribute__((address_space(1))) unsigned*)g,
      (__attribute__((address_space(3))) unsigned*)l, 16, 0, 0);
}

// ---------------- fused fp32 -> bf16 conversion (all 4 tensors) ----------------
__global__ __launch_bounds__(256) void k_cvt4(
    const float* __restrict__ x, const float* __restrict__ Wq,
    const float* __restrict__ Wkv, const float* __restrict__ Wout,
    ushort_t* __restrict__ xb, ushort_t* __restrict__ Wcat,
    ushort_t* __restrict__ Woutb)
{
  int i = blockIdx.x * 256 + threadIdx.x;
  const int stride = gridDim.x * 256;
  for (; i < 5242880; i += stride) {
    const float4* src; ushort4* dst; int off;
    if (i < 4194304)      { src = (const float4*)x;    dst = (ushort4*)xb;                 off = i; }
    else if (i < 4456448) { src = (const float4*)Wq;   dst = (ushort4*)Wcat;               off = i - 4194304; }
    else if (i < 4980736) { src = (const float4*)Wkv;  dst = (ushort4*)(Wcat + 1048576);   off = i - 4456448; }
    else                  { src = (const float4*)Wout; dst = (ushort4*)Woutb;              off = i - 4980736; }
    float4 v = src[off];
    ushort4 o;
    o.x = f2bf(v.x); o.y = f2bf(v.y); o.z = f2bf(v.z); o.w = f2bf(v.w);
    dst[off] = o;
  }
}

// ---------------- 256x256 8-phase GEMM, BK=64, K=1024 fixed ----------------
// C[M][N] = A[M][1024] * Bt[N][1024]^T.  MODE 0: bf16 C.  MODE 2: fp32 C.
// LDS layout: per K-tile buffer, tile rows permuted into "slots" so each
// stage region is LDS-linear; ds_read col XOR-swizzled (T2).
//   A: slot = row with bits 6,7 swapped   (region r = slot>>7 = Qm consumer)
//   B: slot = kk<<5 | q<<7 | low  inverse (region q = slot>>7 = Qn consumer)
// Phase q of tile t reads quadrant (Qm=q>>1, Qn=q&1); region last read at the
// phase listed; staged 1+ phase later => race-free under end-of-phase barrier:
//   A0: last read p1 -> staged p2 (t+2, same buf)   B0: last p2 -> staged p3
//   A1/B1 of t+1 staged p0/p1 into the OTHER buffer (freed since t-1 ended).
// Boundary wait: vmcnt(4) (A0,B0 of t+2 stay in flight) -- never 0 mid-loop.
template<int MODE>
__global__ __launch_bounds__(512, 2) void k_gemm256(
    const ushort_t* __restrict__ A, const ushort_t* __restrict__ Bt,
    void* __restrict__ Cout, int N, int gridN)
{
  __shared__ __align__(16) ushort_t As[2][16384];
  __shared__ __align__(16) ushort_t Bs[2][16384];
  constexpr int K = 1024;
  const int tid = threadIdx.x;
  const int lane = tid & 63, wv = tid >> 6;
  const int wm = wv >> 2, wn = wv & 3;
  const int l15 = lane & 15, lhi = lane >> 4;

  // T1: bijective XCD swizzle (grid sizes are multiples of 8)
  const int nb = gridDim.x * gridDim.y;
  const int lid = blockIdx.y * gridDim.x + blockIdx.x;
  const int swz = (lid & 7) * (nb >> 3) + (lid >> 3);
  const int rowBase = (swz / gridN) * 256;
  const int colBase = (swz % gridN) * 256;

  const ushort_t* Abase = A + (size_t)rowBase * K;
  const ushort_t* Bbase = Bt + (size_t)colBase * K;

  // staging precompute: thread stages 8 elems at slot=so, col=scol of a chunk
  const int so = tid >> 3;           // slot within chunk (64 slots/chunk)
  const int scol = (tid & 7) * 8;
  const int ssw = (so & 7) << 3;     // T2 swizzle (slot&7 == row&7, preserved bits)
  int offA[2][2], offB[2][2];
#pragma unroll
  for (int r = 0; r < 2; ++r)
#pragma unroll
    for (int k = 0; k < 2; ++k) {
      int slot = r*128 + k*64 + so;
      int rowA = ((slot & 64) << 1) | ((slot & 128) >> 1) | (slot & 63);
      int rowB = (((slot >> 5) & 3) << 6) | (((slot >> 7) & 1) << 5) | (slot & 31);
      offA[r][k] = rowA * K + (scol ^ ssw);   // inverse-swizzled global source
      offB[r][k] = rowB * K + (scol ^ ssw);
    }
  const int sbase = wv * 512;        // wave-uniform LDS chunk offset

#define STAGE_A(dst, R, KT) do { \
  gl_lds16(Abase + offA[R][0] + (KT)*64, &As[dst][(R)*8192 + sbase]); \
  gl_lds16(Abase + offA[R][1] + (KT)*64, &As[dst][(R)*8192 + 4096 + sbase]); \
} while(0)
#define STAGE_B(dst, R, KT) do { \
  gl_lds16(Bbase + offB[R][0] + (KT)*64, &Bs[dst][(R)*8192 + sbase]); \
  gl_lds16(Bbase + offB[R][1] + (KT)*64, &Bs[dst][(R)*8192 + 4096 + sbase]); \
} while(0)

  const int fsw = (l15 & 7) << 3;
  const int kc0 = (lhi * 8) ^ fsw;        // swizzled ds_read cols (ks=0,1)
  const int kc1 = (32 + lhi * 8) ^ fsw;

  f32x4 acc[8][4] = {};

#define PHASE(CUR, QM, QN, STAGEOP) do { \
  const ushort_t* Ap = &As[CUR][((QM)*128 + wm*64 + l15)*64]; \
  const ushort_t* Bp = &Bs[CUR][((QN)*128 + wn*32 + l15)*64]; \
  bf16x8 af[4][2], bfr[2][2]; \
  _Pragma("unroll") for (int i_ = 0; i_ < 4; ++i_) { \
    af[i_][0] = *(const bf16x8*)&Ap[i_*1024 + kc0]; \
    af[i_][1] = *(const bf16x8*)&Ap[i_*1024 + kc1]; } \
  _Pragma("unroll") for (int j_ = 0; j_ < 2; ++j_) { \
    bfr[j_][0] = *(const bf16x8*)&Bp[j_*1024 + kc0]; \
    bfr[j_][1] = *(const bf16x8*)&Bp[j_*1024 + kc1]; } \
  STAGEOP; \
  __builtin_amdgcn_s_barrier(); \
  __builtin_amdgcn_s_setprio(1); \
  _Pragma("unroll") for (int i_ = 0; i_ < 4; ++i_) \
  _Pragma("unroll") for (int j_ = 0; j_ < 2; ++j_) { \
    acc[(QM)*4+i_][(QN)*2+j_] = __builtin_amdgcn_mfma_f32_16x16x32_bf16(af[i_][0], bfr[j_][0], acc[(QM)*4+i_][(QN)*2+j_], 0, 0, 0); \
    acc[(QM)*4+i_][(QN)*2+j_] = __builtin_amdgcn_mfma_f32_16x16x32_bf16(af[i_][1], bfr[j_][1], acc[(QM)*4+i_][(QN)*2+j_], 0, 0, 0); } \
  __builtin_amdgcn_s_setprio(0); \
  __builtin_amdgcn_s_barrier(); \
} while(0)

  // prologue: tile0 fully + tile1 A0,B0; drain to 4 outstanding
  STAGE_A(0, 0, 0); STAGE_B(0, 0, 0); STAGE_A(0, 1, 0); STAGE_B(0, 1, 0);
  STAGE_A(1, 0, 1); STAGE_B(1, 0, 1);
  asm volatile("s_waitcnt vmcnt(4)" ::: "memory");
  __builtin_amdgcn_s_barrier();

  for (int t = 0; t < 16; ++t) {
    const int cur = t & 1;
    const int nxt = cur ^ 1;
    const bool s1 = (t < 15), s2 = (t < 14);
    PHASE(cur, 0, 0, if (s1) STAGE_A(nxt, 1, t + 1));
    PHASE(cur, 0, 1, if (s1) STAGE_B(nxt, 1, t + 1));
    PHASE(cur, 1, 0, if (s2) STAGE_A(cur, 0, t + 2));
    PHASE(cur, 1, 1, if (s2) STAGE_B(cur, 0, t + 2));
    if (t < 14) asm volatile("s_waitcnt vmcnt(4)" ::: "memory");
    else        asm volatile("s_waitcnt vmcnt(0)" ::: "memory");
    __builtin_amdgcn_s_barrier();
  }
#undef PHASE
#undef STAGE_A
#undef STAGE_B

  // epilogue: C/D layout col = lane&15, row = (lane>>4)*4 + rr (probe-verified)
  const int orow = rowBase + wm * 128 + lhi * 4;
  const int ocol = colBase + wn * 64 + l15;
#pragma unroll
  for (int i = 0; i < 8; ++i)
#pragma unroll
    for (int j = 0; j < 4; ++j)
#pragma unroll
      for (int rr = 0; rr < 4; ++rr) {
        int gr = orow + i * 16 + rr;
        int gc = ocol + j * 16;
        if (MODE == 2) ((float*)Cout)[(size_t)gr * N + gc] = acc[i][j][rr];
        else           ((ushort_t*)Cout)[(size_t)gr * N + gc] = f2bf(acc[i][j][rr]);
      }
}

// ---------------- per-token attention over HEADS (unchanged, verified) ----------------
__global__ __launch_bounds__(256) void k_attn(
    const ushort_t* __restrict__ qkv, ushort_t* __restrict__ aout)
{
  __shared__ __align__(16) ushort_t qs[4][16*72];
  __shared__ __align__(16) ushort_t kvs[4][16*136];
  __shared__ __align__(16) ushort_t ps[4][16*40];
  __shared__ __align__(16) ushort_t os[4][1024];
  const int tid = threadIdx.x, lane = tid & 63, wave = tid >> 6;
  const int t = blockIdx.x * 4 + wave;
  const int l15 = lane & 15, lhi = lane >> 4;
  const ushort_t* row = qkv + (size_t)t * 3072;

#pragma unroll
  for (int c = 0; c < 6; ++c) {
    int c8 = c * 64 + lane;
    bf16x8 v = *(const bf16x8*)(row + c8 * 8);
    if (c8 < 128) {
      int h = c8 >> 3, off = (c8 & 7) * 8;
      *(bf16x8*)&qs[wave][h*72 + off] = v;
    } else {
      int e = c8 * 8 - 1024;
      int h = e >> 7, off = e & 127;
      *(bf16x8*)&kvs[wave][h*136 + off] = v;
    }
  }
  if (lane < 16) {
    bf16x8 z = {};
    *(bf16x8*)&ps[wave][lane*40 + 16] = z;
    *(bf16x8*)&ps[wave][lane*40 + 24] = z;
  }
  __syncthreads();

  bf16x8 aq0 = *(const bf16x8*)&qs[wave][l15*72 + lhi*8];
  bf16x8 aq1 = *(const bf16x8*)&qs[wave][l15*72 + 32 + lhi*8];
  bf16x8 bk0 = *(const bf16x8*)&kvs[wave][l15*136 + lhi*8];
  bf16x8 bk1 = *(const bf16x8*)&kvs[wave][l15*136 + 32 + lhi*8];
  f32x4 s = {};
  s = __builtin_amdgcn_mfma_f32_16x16x32_bf16(aq0, bk0, s, 0, 0, 0);
  s = __builtin_amdgcn_mfma_f32_16x16x32_bf16(aq1, bk1, s, 0, 0, 0);

#pragma unroll
  for (int r = 0; r < 4; ++r) {
    float sv = s[r] * 0.125f;
    float tm = sv;
#pragma unroll
    for (int off = 1; off < 16; off <<= 1) tm = fmaxf(tm, __shfl_xor(tm, off, 64));
    float p = __expf(sv - tm);
    float rs = p;
#pragma unroll
    for (int off = 1; off < 16; off <<= 1) rs += __shfl_xor(rs, off, 64);
    p /= rs;
    ps[wave][(lhi*4 + r)*40 + l15] = f2bf(p);
  }
  __syncthreads();

  bf16x8 pa = *(const bf16x8*)&ps[wave][l15*40 + lhi*8];
#pragma unroll
  for (int dt = 0; dt < 4; ++dt) {
    bf16x8 vb;
#pragma unroll
    for (int i = 0; i < 8; ++i) {
      int j = (lhi*8 + i) & 15;
      vb[i] = __builtin_bit_cast(__bf16, kvs[wave][j*136 + 64 + dt*16 + l15]);
    }
    f32x4 o = {};
    o = __builtin_amdgcn_mfma_f32_16x16x32_bf16(pa, vb, o, 0, 0, 0);
#pragma unroll
    for (int r = 0; r < 4; ++r)
      os[wave][(lhi*4 + r)*64 + dt*16 + l15] = f2bf(o[r]);
  }
  __syncthreads();

  ushort_t* orow = aout + (size_t)t * 1024;
#pragma unroll
  for (int c = 0; c < 2; ++c) {
    int idx = (c*64 + lane) * 8;
    *(bf16x8*)(orow + idx) = *(const bf16x8*)&os[wave][idx];
  }
}

extern "C" void kernel_launch(void* const* d_in, const int* in_sizes, int n_in,
                              void* d_out, int out_size, void* d_ws, size_t ws_size,
                              hipStream_t stream) {
  const float* x    = (const float*)d_in[0];
  const float* Wq   = (const float*)d_in[1];
  const float* Wkv  = (const float*)d_in[2];
  const float* Wout = (const float*)d_in[3];
  float* out = (float*)d_out;

  ushort_t* ws    = (ushort_t*)d_ws;
  ushort_t* xb    = ws;                          // 16,777,216 elems (reused as aout)
  ushort_t* Wcat  = xb + 16777216;               // 3,145,728  (Wq ; Wkv)
  ushort_t* Woutb = Wcat + 3145728;              // 1,048,576
  ushort_t* qkv   = Woutb + 1048576;             // 50,331,648 ([M][3072])
  ushort_t* aout  = xb;                          // alias: xb dead after gemm1

  // fused fp32 -> bf16
  k_cvt4<<<2048, 256, 0, stream>>>(x, Wq, Wkv, Wout, xb, Wcat, Woutb);

  // QKV projection: [16384 x 1024] x [3072 x 1024]^T -> qkv row-major
  dim3 g1(12, 64);
  k_gemm256<0><<<g1, 512, 0, stream>>>(xb, Wcat, qkv, 3072, 12);

  // per-token attention over heads
  k_attn<<<NM/4, 256, 0, stream>>>(qkv, aout);

  // output projection: [16384 x 1024] x [1024 x 1024]^T -> fp32
  dim3 g3(4, 64);
  k_gemm256<2><<<g3, 512, 0, stream>>>(aout, Woutb, out, 1024, 4);
}